// Round 19
// baseline (373.724 us; speedup 1.0000x reference)
//
#include <hip/hip_runtime.h>
#include <hip/hip_bf16.h>

typedef __hip_bfloat16 bf16;
typedef __attribute__((ext_vector_type(8))) short bf16x8;
typedef __attribute__((ext_vector_type(4))) float f32x4;

constexpr int kEMB = 1024;
constexpr int kHID = 2048;
constexpr int kNH  = 16;
constexpr int kNE  = 8;
constexpr int kL   = 2048;
constexpr int kHD  = 64;
constexpr int kT   = 4096;      // B*L
constexpr int kSLOTS = kT * 2;  // T * TOPK
constexpr int kWIN = 2048;

__device__ __forceinline__ unsigned short f2bfbits(float f){
  bf16 h = __float2bfloat16(f);
  return __builtin_bit_cast(unsigned short, h);
}
__device__ __forceinline__ float bfbits2f(unsigned short u){
  unsigned int x = ((unsigned int)u) << 16;
  return __builtin_bit_cast(float, x);
}
__device__ __forceinline__ void gld_lds16(const void* g, void* s){
  __builtin_amdgcn_global_load_lds((const __attribute__((address_space(1))) void*)g,
                                   (__attribute__((address_space(3))) void*)s, 16, 0, 0);
}
__device__ __forceinline__ float wave_sum64(float v){
  #pragma unroll
  for (int xm = 1; xm < 64; xm <<= 1) v += __shfl_xor(v, xm, 64);
  return v;
}

// ---------------- transpose + fp32->bf16 convert: dst[C][R] = bf16(src[R][C]) ----------------
__global__ __launch_bounds__(256) void tconv_k(const float* __restrict__ src, bf16* __restrict__ dst,
                                               int R, int C){
  __shared__ float tile[32][33];
  const int tx = threadIdx.x & 31, ty = threadIdx.x >> 5;
  const int bx = blockIdx.x * 32, by = blockIdx.y * 32;
  const size_t base = (size_t)blockIdx.z * R * C;
  #pragma unroll
  for (int i = 0; i < 32; i += 8)
    tile[ty + i][tx] = src[base + (size_t)(by + ty + i) * C + bx + tx];
  __syncthreads();
  #pragma unroll
  for (int i = 0; i < 32; i += 8)
    dst[base + (size_t)(bx + ty + i) * R + by + tx] = __float2bfloat16(tile[tx][ty + i]);
}

// 4x same-shape 1024x1024 transposes in one dispatch (z selects source; dst contiguous)
__global__ __launch_bounds__(256) void tconv4_k(const float* __restrict__ s0, const float* __restrict__ s1,
                                                const float* __restrict__ s2, const float* __restrict__ s3,
                                                bf16* __restrict__ dst){
  __shared__ float tile[32][33];
  const int tx = threadIdx.x & 31, ty = threadIdx.x >> 5;
  const int bx = blockIdx.x * 32, by = blockIdx.y * 32;
  const int z = blockIdx.z;
  const float* src = (z == 0) ? s0 : (z == 1) ? s1 : (z == 2) ? s2 : s3;
  bf16* d = dst + (size_t)z * kEMB * kEMB;
  #pragma unroll
  for (int i = 0; i < 32; i += 8)
    tile[ty + i][tx] = src[(size_t)(by + ty + i) * kEMB + bx + tx];
  __syncthreads();
  #pragma unroll
  for (int i = 0; i < 32; i += 8)
    d[(size_t)(bx + ty + i) * kEMB + by + tx] = __float2bfloat16(tile[tx][ty + i]);
}

// ---------------- bf16 transpose per (b,h): [L][HD] -> [HD][L] ----------------
__global__ __launch_bounds__(256) void vtrans_k(const bf16* __restrict__ v, bf16* __restrict__ vt){
  __shared__ unsigned short tile[32][33];
  const int tx = threadIdx.x & 31, ty = threadIdx.x >> 5;
  const int l0 = blockIdx.x * 32, d0 = blockIdx.y * 32;
  const unsigned short* src = (const unsigned short*)v + (size_t)blockIdx.z * kL * kHD;
  unsigned short* dst = (unsigned short*)vt + (size_t)blockIdx.z * kHD * kL;
  #pragma unroll
  for (int i = 0; i < 32; i += 8)
    tile[ty + i][tx] = src[(size_t)(l0 + ty + i) * kHD + d0 + tx];
  __syncthreads();
  #pragma unroll
  for (int i = 0; i < 32; i += 8)
    dst[(size_t)(d0 + ty + i) * kL + l0 + tx] = tile[tx][ty + i];
}

// ---------------- LN1, wave-per-row (no barriers): h = LN(x) ----------------
__global__ __launch_bounds__(256) void lnw_k(
    const float* __restrict__ x, const float* __restrict__ g, const float* __restrict__ bta,
    bf16* __restrict__ h)
{
  const int lane = threadIdx.x & 63, w = threadIdx.x >> 6;
  const int row = blockIdx.x * 4 + w;
  const float4* xr = (const float4*)(x + (size_t)row * kEMB);
  float4 v[4];
  #pragma unroll
  for (int j = 0; j < 4; j++) v[j] = xr[lane + 64 * j];
  float s = 0.f;
  #pragma unroll
  for (int j = 0; j < 4; j++) s += v[j].x + v[j].y + v[j].z + v[j].w;
  s = wave_sum64(s);
  const float mean = s * (1.0f / kEMB);
  float ss = 0.f;
  #pragma unroll
  for (int j = 0; j < 4; j++){
    const float a = v[j].x - mean, b = v[j].y - mean, c = v[j].z - mean, d = v[j].w - mean;
    ss += a*a + b*b + c*c + d*d;
  }
  ss = wave_sum64(ss);
  const float rstd = rsqrtf(ss * (1.0f / kEMB) + 1e-5f);
  unsigned short* hr = (unsigned short*)h + (size_t)row * kEMB;
  #pragma unroll
  for (int j = 0; j < 4; j++){
    const float4 gg = ((const float4*)g)[lane + 64 * j];
    const float4 bb = ((const float4*)bta)[lane + 64 * j];
    ushort4 pk;
    pk.x = f2bfbits((v[j].x - mean) * rstd * gg.x + bb.x);
    pk.y = f2bfbits((v[j].y - mean) * rstd * gg.y + bb.y);
    pk.z = f2bfbits((v[j].z - mean) * rstd * gg.z + bb.z);
    pk.w = f2bfbits((v[j].w - mean) * rstd * gg.w + bb.w);
    *(ushort4*)&hr[(lane + 64 * j) * 4] = pk;
  }
}

// ---------------- LN2 wave-per-row: row = x+P0+P1; out; h2 = LN(row); top-2 router ----------------
__global__ __launch_bounds__(256) void ln2w_k(
    const float* __restrict__ x, const float* __restrict__ P,
    const float* __restrict__ g, const float* __restrict__ bta,
    float* __restrict__ out, bf16* __restrict__ h, const float* __restrict__ Wr,
    int* __restrict__ top_i, float* __restrict__ top_w)
{
  const int lane = threadIdx.x & 63, w = threadIdx.x >> 6;
  const int row = blockIdx.x * 4 + w;
  const float4* xr = (const float4*)(x + (size_t)row * kEMB);
  const float4* p0 = (const float4*)(P + (size_t)row * kEMB);
  const float4* p1 = (const float4*)(P + (size_t)(kT + row) * kEMB);
  float4* outr = (float4*)(out + (size_t)row * kEMB);
  float4 v[4];
  #pragma unroll
  for (int j = 0; j < 4; j++){
    const float4 a = xr[lane + 64 * j], b = p0[lane + 64 * j], c = p1[lane + 64 * j];
    v[j].x = a.x + b.x + c.x; v[j].y = a.y + b.y + c.y;
    v[j].z = a.z + b.z + c.z; v[j].w = a.w + b.w + c.w;
    outr[lane + 64 * j] = v[j];
  }
  float s = 0.f;
  #pragma unroll
  for (int j = 0; j < 4; j++) s += v[j].x + v[j].y + v[j].z + v[j].w;
  s = wave_sum64(s);
  const float mean = s * (1.0f / kEMB);
  float ss = 0.f;
  #pragma unroll
  for (int j = 0; j < 4; j++){
    const float a = v[j].x - mean, b = v[j].y - mean, c = v[j].z - mean, d = v[j].w - mean;
    ss += a*a + b*b + c*c + d*d;
  }
  ss = wave_sum64(ss);
  const float rstd = rsqrtf(ss * (1.0f / kEMB) + 1e-5f);
  unsigned short* hr = (unsigned short*)h + (size_t)row * kEMB;
  float part[8];
  #pragma unroll
  for (int e = 0; e < 8; e++) part[e] = 0.f;
  #pragma unroll
  for (int j = 0; j < 4; j++){
    const float4 gg = ((const float4*)g)[lane + 64 * j];
    const float4 bb = ((const float4*)bta)[lane + 64 * j];
    float n[4];
    n[0] = (v[j].x - mean) * rstd * gg.x + bb.x;
    n[1] = (v[j].y - mean) * rstd * gg.y + bb.y;
    n[2] = (v[j].z - mean) * rstd * gg.z + bb.z;
    n[3] = (v[j].w - mean) * rstd * gg.w + bb.w;
    ushort4 pk;
    pk.x = f2bfbits(n[0]); pk.y = f2bfbits(n[1]); pk.z = f2bfbits(n[2]); pk.w = f2bfbits(n[3]);
    *(ushort4*)&hr[(lane + 64 * j) * 4] = pk;
    const float* wrp = Wr + (size_t)(lane + 64 * j) * 4 * kNE;
    #pragma unroll
    for (int i = 0; i < 4; i++)
      #pragma unroll
      for (int e = 0; e < 8; e++) part[e] += n[i] * wrp[i * kNE + e];
  }
  #pragma unroll
  for (int xm = 1; xm < 64; xm <<= 1)
    #pragma unroll
    for (int e = 0; e < 8; e++) part[e] += __shfl_xor(part[e], xm, 64);
  if (lane == 0){
    int i0 = 0; float v0 = part[0];
    #pragma unroll
    for (int e = 1; e < 8; e++) if (part[e] > v0){ v0 = part[e]; i0 = e; }
    int i1 = -1; float v1 = -3.4e38f;
    #pragma unroll
    for (int e = 0; e < 8; e++) if (e != i0 && part[e] > v1){ v1 = part[e]; i1 = e; }
    const float w0 = 1.0f / (1.0f + __expf(v1 - v0));
    top_i[row * 2] = i0; top_i[row * 2 + 1] = i1;
    top_w[row * 2] = w0; top_w[row * 2 + 1] = 1.0f - w0;
  }
}

// ---------------- 128x128 bf16 MFMA GEMM, dbuf (R4-proven loop) — dense modes ----------------
// MODE 1: split-K x2 (blockIdx.z = half), fdst[z*kT*kEMB + ...] = partial fp32
// MODE 4: fused QKV: N=3072, sec=gn>>10 -> q(*0.125*log2e)/k/v scattered to [b,h,l,d]
template<int MODE>
__global__ __launch_bounds__(256) void gemm_k(
    const bf16* __restrict__ A, const bf16* __restrict__ BT, int K,
    float* __restrict__ fdst, bf16* __restrict__ bdst)
{
  __shared__ alignas(16) unsigned short As[2][128 * 64];
  __shared__ alignas(16) unsigned short Bs[2][128 * 64];
  const int tid = threadIdx.x, lane = tid & 63, w = tid >> 6;
  const int wr = w >> 1, wc = w & 1;
  const int bx = blockIdx.x, by = blockIdx.y;
  int kt0 = 0, nkt = K / 64;
  if (MODE == 1){ kt0 = blockIdx.z * (K / 2); nkt = K / 128; }
  const int m0 = by * 128, n0 = bx * 128;
  f32x4 acc[4][4] = {};
  const int srow = lane >> 3;          // 0..7
  const int skk  = (lane & 7) * 8;     // k elems (16B chunks)

  auto stage = [&](int t, int buf){
    const int kt = kt0 + t * 64;
    #pragma unroll
    for (int j = 0; j < 4; j++){
      const int rr = w * 32 + j * 8;
      gld_lds16(A + (size_t)(m0 + rr + srow) * K + kt + skk, &As[buf][rr * 64]);
      gld_lds16(BT + (size_t)(n0 + rr + srow) * K + kt + skk, &Bs[buf][rr * 64]);
    }
  };

  stage(0, 0);
  __syncthreads();
  for (int t = 0; t < nkt; t++){
    const int cur = t & 1;
    if (t + 1 < nkt) stage(t + 1, cur ^ 1);
    #pragma unroll
    for (int ks = 0; ks < 2; ks++){
      bf16x8 af[4], bfm[4];
      #pragma unroll
      for (int i = 0; i < 4; i++){
        af[i]  = *(const bf16x8*)&As[cur][(wr * 64 + i * 16 + (lane & 15)) * 64 + ks * 32 + (lane >> 4) * 8];
        bfm[i] = *(const bf16x8*)&Bs[cur][(wc * 64 + i * 16 + (lane & 15)) * 64 + ks * 32 + (lane >> 4) * 8];
      }
      #pragma unroll
      for (int i = 0; i < 4; i++)
        #pragma unroll
        for (int j = 0; j < 4; j++)
          acc[i][j] = __builtin_amdgcn_mfma_f32_16x16x32_bf16(af[i], bfm[j], acc[i][j], 0, 0, 0);
    }
    __syncthreads();
  }

  #pragma unroll
  for (int i = 0; i < 4; i++){
    #pragma unroll
    for (int r = 0; r < 4; r++){
      const int gm = m0 + wr * 64 + i * 16 + (lane >> 4) * 4 + r;
      if (MODE == 1){
        float* pdst = fdst + (size_t)blockIdx.z * kT * kEMB;
        #pragma unroll
        for (int jn = 0; jn < 4; jn++){
          const int gn = n0 + wc * 64 + jn * 16 + (lane & 15);
          pdst[(size_t)gm * kEMB + gn] = acc[i][jn][r];
        }
      } else { // MODE 4
        const int bidx = gm >> 11, l = gm & (kL - 1);
        #pragma unroll
        for (int jn = 0; jn < 4; jn++){
          const int gn = n0 + wc * 64 + jn * 16 + (lane & 15);
          const int sec = gn >> 10;
          const int nn = gn & 1023;
          const int hh = nn >> 6, d = nn & 63;
          // q scale folds 1/sqrt(HD) * log2(e) so attention softmax runs in base 2
          const float val = acc[i][jn][r] * (sec == 0 ? 0.18033688f : 1.0f);
          bdst[(size_t)sec * kT * kEMB + (((size_t)bidx * kNH + hh) * kL + l) * kHD + d] =
              __float2bfloat16(val);
        }
      }
    }
  }
}

// ---------------- grouped MoE GEMM: 128x128, BK=32, A-triple/B-double, one-barrier counted-vmcnt ----------------
// MODE 2: A gathered via rowtok, out = silu(C+bias) [NB=2048, K=1024]
// MODE 3: A contiguous, split-K x2 (bit3 of bid = half), partial (C + bias@half0)*roww -> bdst/bdstB bf16
template<int MODE>
__global__ __launch_bounds__(256, 4) void gemm3_k(
    const bf16* __restrict__ A, const bf16* __restrict__ BT, int K,
    bf16* __restrict__ bdst, bf16* __restrict__ bdstB, const float* __restrict__ bias,
    const float* __restrict__ roww, const int* __restrict__ rowtok,
    const int* __restrict__ offs)
{
  __shared__ alignas(16) unsigned short As[3][128 * 32];
  __shared__ alignas(16) unsigned short Bs[2][128 * 32];
  const int tid = threadIdx.x, lane = tid & 63, w = tid >> 6;
  const int wr = w >> 1, wc = w & 1;
  int e, bx, by, half = 0;
  if (MODE == 2){
    e = blockIdx.x & 7; const int s = blockIdx.x >> 3; by = s >> 4; bx = s & 15;
  } else {
    e = blockIdx.x & 7; half = (blockIdx.x >> 3) & 1;
    const int s2 = blockIdx.x >> 4; bx = s2 & 7; by = s2 >> 3;
  }
  const int rbase = offs[e], rend = offs[e + 1];
  if (by * 128 >= rend - rbase) return;
  const int m0 = by * 128, n0 = bx * 128;
  const int NB = (MODE == 2) ? kHID : kEMB;
  const bf16* Bp = BT + (size_t)e * NB * K;
  const float* biasp = bias + e * NB;
  const int kt0 = (MODE == 3) ? half * (K / 2) : 0;
  const int nkt = ((MODE == 3) ? K / 2 : K) / 32;
  f32x4 acc[4][4] = {};

  // staging map: chunk sc=tid&3 (16B), row sr0=tid>>2 (pass0) / 64+sr0 (pass1)
  const int sc = tid & 3, sr0 = tid >> 2;
  const int scs = (sc ^ (sr0 & 3)) * 8;       // pre-swizzled source col (elems)
  size_t aoffs[2]; size_t boffs[2];
  {
    int p0 = rbase + m0 + sr0;      if (p0 >= rend) p0 = rbase;
    int p1 = rbase + m0 + 64 + sr0; if (p1 >= rend) p1 = rbase;
    aoffs[0] = (size_t)((MODE == 2) ? rowtok[p0] : p0) * K;
    aoffs[1] = (size_t)((MODE == 2) ? rowtok[p1] : p1) * K;
    boffs[0] = (size_t)(n0 + sr0) * K;
    boffs[1] = (size_t)(n0 + 64 + sr0) * K;
  }

  auto stageA = [&](int t){
    const int b = t % 3; const int kt = kt0 + t * 32;
    gld_lds16(A + aoffs[0] + kt + scs, &As[b][tid * 8]);
    gld_lds16(A + aoffs[1] + kt + scs, &As[b][(tid + 256) * 8]);
  };
  auto stageB = [&](int t){
    const int b = t & 1; const int kt = kt0 + t * 32;
    gld_lds16(Bp + boffs[0] + kt + scs, &Bs[b][tid * 8]);
    gld_lds16(Bp + boffs[1] + kt + scs, &Bs[b][(tid + 256) * 8]);
  };

  // prologue: B(0), A(0), A(1)
  stageB(0);
  stageA(0);
  if (nkt > 1) stageA(1);
  asm volatile("s_waitcnt vmcnt(0)" ::: "memory");
  __builtin_amdgcn_s_barrier();

  for (int t = 0; t < nkt; t++){
    if (t > 0){
      if (t + 1 < nkt) { asm volatile("s_waitcnt vmcnt(2)" ::: "memory"); }
      else             { asm volatile("s_waitcnt vmcnt(0)" ::: "memory"); }
      __builtin_amdgcn_s_barrier();
    }
    const int ca = t % 3, cb = t & 1;
    bf16x8 af[4], bfm[4];
    const int cc = lane >> 4;          // 16B chunk 0..3
    #pragma unroll
    for (int i = 0; i < 4; i++){
      const int ar = wr * 64 + i * 16 + (lane & 15);
      af[i] = *(const bf16x8*)&As[ca][ar * 32 + ((cc ^ (ar & 3)) * 8)];
    }
    #pragma unroll
    for (int j = 0; j < 4; j++){
      const int br = wc * 64 + j * 16 + (lane & 15);
      bfm[j] = *(const bf16x8*)&Bs[cb][br * 32 + ((cc ^ (br & 3)) * 8)];
    }
    __builtin_amdgcn_s_setprio(1);
    #pragma unroll
    for (int i = 0; i < 4; i++)
      #pragma unroll
      for (int j = 0; j < 4; j++)
        acc[i][j] = __builtin_amdgcn_mfma_f32_16x16x32_bf16(af[i], bfm[j], acc[i][j], 0, 0, 0);
    __builtin_amdgcn_s_setprio(0);
    if (t + 1 < nkt) stageB(t + 1);
    if (t + 2 < nkt) stageA(t + 2);
  }

  #pragma unroll
  for (int i = 0; i < 4; i++){
    #pragma unroll
    for (int r = 0; r < 4; r++){
      const int p = rbase + m0 + wr * 64 + i * 16 + (lane >> 4) * 4 + r;
      if (p < rend){
        if (MODE == 2){
          #pragma unroll
          for (int jn = 0; jn < 4; jn++){
            const int gn = n0 + wc * 64 + jn * 16 + (lane & 15);
            const float vv = acc[i][jn][r] + biasp[gn];
            bdst[(size_t)p * kHID + gn] = __float2bfloat16(vv / (1.0f + __expf(-vv)));
          }
        } else {
          const float wgt = roww[p];
          bf16* dst = half ? bdstB : bdst;
          #pragma unroll
          for (int jn = 0; jn < 4; jn++){
            const int gn = n0 + wc * 64 + jn * 16 + (lane & 15);
            const float bb = half ? 0.f : biasp[gn];   // bias added once (half 0)
            dst[(size_t)p * kEMB + gn] = __float2bfloat16((acc[i][jn][r] + bb) * wgt);
          }
        }
      }
    }
  }
}

// ---------------- flash attention: 64 q-rows/block, deferred-reduce base-2 softmax ----------------
__global__ __launch_bounds__(256) void attn_k(
    const bf16* __restrict__ q, const bf16* __restrict__ k, const bf16* __restrict__ vt,
    bf16* __restrict__ o, const int* __restrict__ pos)
{
  const int bid = blockIdx.x;
  const int qt = 31 - (bid >> 5);        // descending work order (longest first)
  const int bh = bid & 31;               // bh fastest -> per-XCD K/V L2 affinity
  const int tid = threadIdx.x, lane = tid & 63, w = tid >> 6;
  const unsigned short* qp  = (const unsigned short*)q  + (size_t)bh * kL * kHD;
  const unsigned short* kp  = (const unsigned short*)k  + (size_t)bh * kL * kHD;
  const unsigned short* vtp = (const unsigned short*)vt + (size_t)bh * kHD * kL;
  __shared__ alignas(16) unsigned short Ks[2][64 * 64];   // K[key][d], chunk-swizzled
  __shared__ alignas(16) unsigned short Vt[2][64 * 64];   // V^T[d][key], chunk-swizzled
  __shared__ alignas(16) unsigned short pl[4 * 16 * 72];  // per-wave P [row][key] padded
  const int q0 = qt * 64 + w * 16;
  const int pos0 = pos[0];
  const int wlo = pos0 - kWIN;

  bf16x8 qf[2];
  {
    const int qrow = q0 + (lane & 15);
    #pragma unroll
    for (int ks = 0; ks < 2; ks++)
      qf[ks] = *(const bf16x8*)&qp[(size_t)qrow * kHD + ks * 32 + (lane >> 4) * 8];
  }
  float m_run[4], l_part[4];
  f32x4 oacc[4] = {};
  #pragma unroll
  for (int r = 0; r < 4; r++){ m_run[r] = -1e30f; l_part[r] = 0.f; }

  // stage tile kt into buf: LDS(row, c') = G(row, c'^(row&7)); 16B chunks
  auto stage = [&](int kt, int buf){
    #pragma unroll
    for (int j = 0; j < 2; j++){
      const int r = w * 16 + j * 8 + (lane >> 3);
      const int c = (lane & 7) ^ (r & 7);
      gld_lds16(kp  + (size_t)(kt * 64 + r) * 64 + c * 8, &Ks[buf][(w * 16 + j * 8) * 64]);
      gld_lds16(vtp + (size_t)r * kL + kt * 64 + c * 8,   &Vt[buf][(w * 16 + j * 8) * 64]);
    }
  };

  stage(0, 0);
  for (int kt = 0; kt <= qt; kt++){
    const int buf = kt & 1;
    __syncthreads();               // drains vmcnt -> this tile's stage complete everywhere
    if (kt < qt) stage(kt + 1, buf ^ 1);

    // QK^T (base-2 scaled)
    f32x4 s[4];
    #pragma unroll
    for (int kbk = 0; kbk < 4; kbk++){
      const int row = kbk * 16 + (lane & 15);
      f32x4 a = {0.f, 0.f, 0.f, 0.f};
      #pragma unroll
      for (int ks = 0; ks < 2; ks++){
        const int chnk = ks * 4 + (lane >> 4);
        const bf16x8 kf = *(const bf16x8*)&Ks[buf][row * 64 + ((chnk ^ (row & 7)) * 8)];
        a = __builtin_amdgcn_mfma_f32_16x16x32_bf16(qf[ks], kf, a, 0, 0, 0);
      }
      s[kbk] = a;
    }
    // mask only on diagonal / window-cut tiles (wave-uniform branch)
    const bool needmask = (kt == qt) || (kt * 64 < q0 + 16 + wlo);
    if (needmask){
      #pragma unroll
      for (int kbk = 0; kbk < 4; kbk++){
        const int j = kt * 64 + kbk * 16 + (lane & 15);
        #pragma unroll
        for (int r = 0; r < 4; r++){
          const int i = q0 + (lane >> 4) * 4 + r;
          if (j > i || j < i + wlo) s[kbk][r] = -1e30f;
        }
      }
    }
    // per-lane tile max (no cross-lane reduce on the common path)
    float pmax[4];
    #pragma unroll
    for (int r = 0; r < 4; r++) pmax[r] = s[0][r];
    #pragma unroll
    for (int kbk = 1; kbk < 4; kbk++)
      #pragma unroll
      for (int r = 0; r < 4; r++) pmax[r] = fmaxf(pmax[r], s[kbk][r]);
    bool need = false;
    #pragma unroll
    for (int r = 0; r < 4; r++) need |= (pmax[r] > m_run[r] + 8.0f);
    if (__any(need)){
      float tm[4];
      #pragma unroll
      for (int r = 0; r < 4; r++) tm[r] = pmax[r];
      #pragma unroll
      for (int xm = 1; xm < 16; xm <<= 1)
        #pragma unroll
        for (int r = 0; r < 4; r++) tm[r] = fmaxf(tm[r], __shfl_xor(tm[r], xm, 64));
      #pragma unroll
      for (int r = 0; r < 4; r++){
        const float mn = fmaxf(m_run[r], tm[r]);
        const float corr = exp2f(m_run[r] - mn);
        m_run[r] = mn;
        l_part[r] *= corr;
        #pragma unroll
        for (int db = 0; db < 4; db++) oacc[db][r] *= corr;
      }
    }
    // P = 2^(s - m_run) (bounded by 2^8); per-lane l accumulation only
    #pragma unroll
    for (int kbk = 0; kbk < 4; kbk++)
      #pragma unroll
      for (int r = 0; r < 4; r++){
        const float p = exp2f(s[kbk][r] - m_run[r]);
        s[kbk][r] = p;
        l_part[r] += p;
      }
    // P -> LDS (per-wave region) -> A-fragments
    #pragma unroll
    for (int kbk = 0; kbk < 4; kbk++)
      #pragma unroll
      for (int r = 0; r < 4; r++)
        pl[(w * 16 + (lane >> 4) * 4 + r) * 72 + kbk * 16 + (lane & 15)] = f2bfbits(s[kbk][r]);
    asm volatile("s_waitcnt lgkmcnt(0)" ::: "memory");
    __builtin_amdgcn_sched_barrier(0);
    bf16x8 pa[2];
    #pragma unroll
    for (int ks = 0; ks < 2; ks++)
      pa[ks] = *(const bf16x8*)&pl[(w * 16 + (lane & 15)) * 72 + ks * 32 + (lane >> 4) * 8];
    // PV
    #pragma unroll
    for (int db = 0; db < 4; db++){
      const int row = db * 16 + (lane & 15);
      #pragma unroll
      for (int ks = 0; ks < 2; ks++){
        const int chnk = ks * 4 + (lane >> 4);
        const bf16x8 vf = *(const bf16x8*)&Vt[buf][row * 64 + ((chnk ^ (row & 7)) * 8)];
        oacc[db] = __builtin_amdgcn_mfma_f32_16x16x32_bf16(pa[ks], vf, oacc[db], 0, 0, 0);
      }
    }
  }
  // epilogue: single cross-lane l reduce (16-lane row groups)
  #pragma unroll
  for (int xm = 1; xm < 16; xm <<= 1)
    #pragma unroll
    for (int r = 0; r < 4; r++) l_part[r] += __shfl_xor(l_part[r], xm, 64);
  const int hh = bh & (kNH - 1), bidx = bh >> 4;
  #pragma unroll
  for (int db = 0; db < 4; db++){
    #pragma unroll
    for (int r = 0; r < 4; r++){
      const int i = q0 + (lane >> 4) * 4 + r;
      const int d = db * 16 + (lane & 15);
      o[((size_t)(bidx * kL + i)) * kEMB + hh * kHD + d] = __float2bfloat16(oacc[db][r] / l_part[r]);
    }
  }
}

// ---------------- routing ----------------
// single-block histogram + scan (replaces zero/count/scan)
__global__ void hist_k(const int* __restrict__ top_i, int* __restrict__ offs, int* __restrict__ cursor){
  __shared__ int lc[kNE];
  if (threadIdx.x < kNE) lc[threadIdx.x] = 0;
  __syncthreads();
  for (int i = threadIdx.x; i < kSLOTS; i += 256) atomicAdd(&lc[top_i[i]], 1);
  __syncthreads();
  if (threadIdx.x == 0){
    int o = 0;
    for (int e = 0; e < kNE; e++){ offs[e] = o; cursor[e] = o; o += lc[e]; }
    offs[kNE] = o;
  }
}

__global__ __launch_bounds__(256) void assign_k(const int* __restrict__ top_i, const float* __restrict__ top_w,
                                                int* __restrict__ cursor, int* __restrict__ rowtok,
                                                float* __restrict__ roww, int* __restrict__ tok2row){
  const int idx = blockIdx.x * 256 + threadIdx.x;
  if (idx < kSLOTS){
    const int e = top_i[idx];
    const int p = atomicAdd(&cursor[e], 1);
    rowtok[p] = idx >> 1;
    roww[p] = top_w[idx];
    tok2row[idx] = p;
  }
}

// combine: out += sum of both split-K partials for both expert slots
__global__ __launch_bounds__(256) void combine_k(float* __restrict__ out, const bf16* __restrict__ g2,
                                                 const bf16* __restrict__ g2b,
                                                 const int* __restrict__ tok2row){
  const int t = blockIdx.x, c = threadIdx.x * 4;
  const int r0 = tok2row[t * 2], r1 = tok2row[t * 2 + 1];
  const ushort4 ua = *(const ushort4*)((const unsigned short*)g2  + (size_t)r0 * kEMB + c);
  const ushort4 ub = *(const ushort4*)((const unsigned short*)g2  + (size_t)r1 * kEMB + c);
  const ushort4 uc = *(const ushort4*)((const unsigned short*)g2b + (size_t)r0 * kEMB + c);
  const ushort4 ud = *(const ushort4*)((const unsigned short*)g2b + (size_t)r1 * kEMB + c);
  float* op = out + (size_t)t * kEMB + c;
  float4 ov = *(float4*)op;
  ov.x += bfbits2f(ua.x) + bfbits2f(ub.x) + bfbits2f(uc.x) + bfbits2f(ud.x);
  ov.y += bfbits2f(ua.y) + bfbits2f(ub.y) + bfbits2f(uc.y) + bfbits2f(ud.y);
  ov.z += bfbits2f(ua.z) + bfbits2f(ub.z) + bfbits2f(uc.z) + bfbits2f(ud.z);
  ov.w += bfbits2f(ua.w) + bfbits2f(ub.w) + bfbits2f(uc.w) + bfbits2f(ud.w);
  *(float4*)op = ov;
}

// ---------------- launch ----------------
extern "C" void kernel_launch(void* const* d_in, const int* in_sizes, int n_in,
                              void* d_out, int out_size, void* d_ws, size_t ws_size,
                              hipStream_t stream)
{
  const float* x    = (const float*)d_in[0];
  const int*   pos  = (const int*)d_in[1];
  const float* ln1g = (const float*)d_in[2];
  const float* ln1b = (const float*)d_in[3];
  const float* ln2g = (const float*)d_in[4];
  const float* ln2b = (const float*)d_in[5];
  const float* Wq   = (const float*)d_in[6];
  const float* Wk   = (const float*)d_in[7];
  const float* Wv   = (const float*)d_in[8];
  const float* Wo   = (const float*)d_in[9];
  const float* Wr   = (const float*)d_in[10];
  const float* W1   = (const float*)d_in[11];
  const float* b1   = (const float*)d_in[12];
  const float* W2   = (const float*)d_in[13];
  const float* b2   = (const float*)d_in[14];
  float* out = (float*)d_out;

  char* p = (char*)d_ws;
  auto alloc = [&](size_t bytes) -> char* {
    char* r = p; p += (bytes + 255) & ~(size_t)255; return r;
  };
  bf16* WqkvT = (bf16*)alloc((size_t)3 * kEMB * kEMB * 2);  // WqT|WkT|WvT contiguous
  bf16* WoT   = (bf16*)alloc((size_t)kEMB * kEMB * 2);      // contiguous after WqkvT
  bf16* W1T   = (bf16*)alloc((size_t)kNE * kEMB * kHID * 2);
  bf16* W2T   = (bf16*)alloc((size_t)kNE * kEMB * kHID * 2);
  bf16* hbf   = (bf16*)alloc((size_t)kT * kEMB * 2);        // } dead after attn ->
  bf16* qkv   = (bf16*)alloc((size_t)3 * kT * kEMB * 2);    // } reused as Pws, then g2 half-1
  bf16* vtbf  = (bf16*)alloc((size_t)kT * kEMB * 2);
  bf16* abf   = (bf16*)alloc((size_t)kT * kEMB * 2);
  bf16* h2bf  = (bf16*)alloc((size_t)kT * kEMB * 2);
  bf16* hebf  = (bf16*)alloc((size_t)kSLOTS * kHID * 2);
  bf16* g2bf  = (bf16*)alloc((size_t)kSLOTS * kEMB * 2);
  int*   top_i   = (int*)alloc(kSLOTS * 4);
  float* top_w   = (float*)alloc(kSLOTS * 4);
  int*   offs    = (int*)alloc(64);
  int*   cursor  = (int*)alloc(64);
  int*   rowtok  = (int*)alloc(kSLOTS * 4);
  float* rowwgt  = (float*)alloc(kSLOTS * 4);
  int*   tok2row = (int*)alloc(kSLOTS * 4);
  bf16* qbf = qkv;
  bf16* kbf = qkv + (size_t)kT * kEMB;
  bf16* vbf = qkv + (size_t)2 * kT * kEMB;
  float* Pws = (float*)hbf;     // 2 x kT x kEMB fp32 split-K partials (spans hbf+qkv; dead after ln2w)
  bf16* g2bf2 = (bf16*)hbf;     // W2 split-K half-1 partial (16MB, reuses dead Pws region)
  (void)in_sizes; (void)n_in; (void)out_size; (void)ws_size;

  // weights -> bf16 transposed (Wq|Wk|Wv|Wo in one dispatch; WoT contiguous after WqkvT)
  tconv4_k<<<dim3(32, 32, 4), 256, 0, stream>>>(Wq, Wk, Wv, Wo, WqkvT);
  tconv_k<<<dim3(64, 32, kNE), 256, 0, stream>>>(W1, W1T, kEMB, kHID);
  tconv_k<<<dim3(32, 64, kNE), 256, 0, stream>>>(W2, W2T, kHID, kEMB);

  // LN1 (wave-per-row)
  lnw_k<<<kT / 4, 256, 0, stream>>>(x, ln1g, ln1b, hbf);

  // fused QKV projection (N=3072; q pre-scaled by 1/sqrt(HD)*log2e)
  gemm_k<4><<<dim3(24, 32), 256, 0, stream>>>(hbf, WqkvT, kEMB, nullptr, qkv);

  // V -> V^T per (b,h)
  vtrans_k<<<dim3(kL / 32, kHD / 32, 32), 256, 0, stream>>>(vbf, vtbf);

  // attention (64 q-rows/block, 1024 blocks)
  attn_k<<<dim3(1024), 256, 0, stream>>>(qbf, kbf, vtbf, abf, pos);

  // Wo split-K x2 -> fp32 partials (residual merge fused into ln2w_k)
  gemm_k<1><<<dim3(8, 32, 2), 256, 0, stream>>>(abf, WoT, kEMB, Pws, nullptr);

  // LN2 + merge + router (wave-per-row, no barriers)
  ln2w_k<<<kT / 4, 256, 0, stream>>>(x, Pws, ln2g, ln2b, out, h2bf, Wr, top_i, top_w);

  // routing (fused histogram+scan, then assign)
  hist_k<<<1, 256, 0, stream>>>(top_i, offs, cursor);
  assign_k<<<kSLOTS / 256, 256, 0, stream>>>(top_i, top_w, cursor, rowtok, rowwgt, tok2row);

  // grouped MoE FFN: W1 as before; W2 split-K x2 (bf16 dual partials, merged in combine)
  gemm3_k<2><<<dim3(8 * 32 * 16), 256, 0, stream>>>(h2bf, W1T, kEMB, hebf, nullptr, b1, nullptr, rowtok, offs);
  gemm3_k<3><<<dim3(8 * 2 * 8 * 32), 256, 0, stream>>>(hebf, W2T, kHID, g2bf, g2bf2, b2, rowwgt, nullptr, offs);

  // combine (sums both partials for both slots)
  combine_k<<<kT, 256, 0, stream>>>(out, g2bf, g2bf2, tok2row);
}

// Round 20
// 344.955 us; speedup vs baseline: 1.0834x; 1.0834x over previous
//
#include <hip/hip_runtime.h>
#include <hip/hip_bf16.h>

typedef __hip_bfloat16 bf16;
typedef __attribute__((ext_vector_type(8))) short bf16x8;
typedef __attribute__((ext_vector_type(4))) float f32x4;

constexpr int kEMB = 1024;
constexpr int kHID = 2048;
constexpr int kNH  = 16;
constexpr int kNE  = 8;
constexpr int kL   = 2048;
constexpr int kHD  = 64;
constexpr int kT   = 4096;      // B*L
constexpr int kSLOTS = kT * 2;  // T * TOPK
constexpr int kWIN = 2048;

__device__ __forceinline__ unsigned short f2bfbits(float f){
  bf16 h = __float2bfloat16(f);
  return __builtin_bit_cast(unsigned short, h);
}
__device__ __forceinline__ float bfbits2f(unsigned short u){
  unsigned int x = ((unsigned int)u) << 16;
  return __builtin_bit_cast(float, x);
}
__device__ __forceinline__ void gld_lds16(const void* g, void* s){
  __builtin_amdgcn_global_load_lds((const __attribute__((address_space(1))) void*)g,
                                   (__attribute__((address_space(3))) void*)s, 16, 0, 0);
}
__device__ __forceinline__ float wave_sum64(float v){
  #pragma unroll
  for (int xm = 1; xm < 64; xm <<= 1) v += __shfl_xor(v, xm, 64);
  return v;
}

// ---------------- transpose + fp32->bf16 convert: dst[C][R] = bf16(src[R][C]) ----------------
__global__ __launch_bounds__(256) void tconv_k(const float* __restrict__ src, bf16* __restrict__ dst,
                                               int R, int C){
  __shared__ float tile[32][33];
  const int tx = threadIdx.x & 31, ty = threadIdx.x >> 5;
  const int bx = blockIdx.x * 32, by = blockIdx.y * 32;
  const size_t base = (size_t)blockIdx.z * R * C;
  #pragma unroll
  for (int i = 0; i < 32; i += 8)
    tile[ty + i][tx] = src[base + (size_t)(by + ty + i) * C + bx + tx];
  __syncthreads();
  #pragma unroll
  for (int i = 0; i < 32; i += 8)
    dst[base + (size_t)(bx + ty + i) * R + by + tx] = __float2bfloat16(tile[tx][ty + i]);
}

// 4x same-shape 1024x1024 transposes in one dispatch (z selects source; dst contiguous)
__global__ __launch_bounds__(256) void tconv4_k(const float* __restrict__ s0, const float* __restrict__ s1,
                                                const float* __restrict__ s2, const float* __restrict__ s3,
                                                bf16* __restrict__ dst){
  __shared__ float tile[32][33];
  const int tx = threadIdx.x & 31, ty = threadIdx.x >> 5;
  const int bx = blockIdx.x * 32, by = blockIdx.y * 32;
  const int z = blockIdx.z;
  const float* src = (z == 0) ? s0 : (z == 1) ? s1 : (z == 2) ? s2 : s3;
  bf16* d = dst + (size_t)z * kEMB * kEMB;
  #pragma unroll
  for (int i = 0; i < 32; i += 8)
    tile[ty + i][tx] = src[(size_t)(by + ty + i) * kEMB + bx + tx];
  __syncthreads();
  #pragma unroll
  for (int i = 0; i < 32; i += 8)
    d[(size_t)(bx + ty + i) * kEMB + by + tx] = __float2bfloat16(tile[tx][ty + i]);
}

// ---------------- bf16 transpose per (b,h): [L][HD] -> [HD][L] ----------------
__global__ __launch_bounds__(256) void vtrans_k(const bf16* __restrict__ v, bf16* __restrict__ vt){
  __shared__ unsigned short tile[32][33];
  const int tx = threadIdx.x & 31, ty = threadIdx.x >> 5;
  const int l0 = blockIdx.x * 32, d0 = blockIdx.y * 32;
  const unsigned short* src = (const unsigned short*)v + (size_t)blockIdx.z * kL * kHD;
  unsigned short* dst = (unsigned short*)vt + (size_t)blockIdx.z * kHD * kL;
  #pragma unroll
  for (int i = 0; i < 32; i += 8)
    tile[ty + i][tx] = src[(size_t)(l0 + ty + i) * kHD + d0 + tx];
  __syncthreads();
  #pragma unroll
  for (int i = 0; i < 32; i += 8)
    dst[(size_t)(d0 + ty + i) * kL + l0 + tx] = tile[tx][ty + i];
}

// ---------------- LN1, wave-per-row (no barriers): h = LN(x) ----------------
__global__ __launch_bounds__(256) void lnw_k(
    const float* __restrict__ x, const float* __restrict__ g, const float* __restrict__ bta,
    bf16* __restrict__ h)
{
  const int lane = threadIdx.x & 63, w = threadIdx.x >> 6;
  const int row = blockIdx.x * 4 + w;
  const float4* xr = (const float4*)(x + (size_t)row * kEMB);
  float4 v[4];
  #pragma unroll
  for (int j = 0; j < 4; j++) v[j] = xr[lane + 64 * j];
  float s = 0.f;
  #pragma unroll
  for (int j = 0; j < 4; j++) s += v[j].x + v[j].y + v[j].z + v[j].w;
  s = wave_sum64(s);
  const float mean = s * (1.0f / kEMB);
  float ss = 0.f;
  #pragma unroll
  for (int j = 0; j < 4; j++){
    const float a = v[j].x - mean, b = v[j].y - mean, c = v[j].z - mean, d = v[j].w - mean;
    ss += a*a + b*b + c*c + d*d;
  }
  ss = wave_sum64(ss);
  const float rstd = rsqrtf(ss * (1.0f / kEMB) + 1e-5f);
  unsigned short* hr = (unsigned short*)h + (size_t)row * kEMB;
  #pragma unroll
  for (int j = 0; j < 4; j++){
    const float4 gg = ((const float4*)g)[lane + 64 * j];
    const float4 bb = ((const float4*)bta)[lane + 64 * j];
    ushort4 pk;
    pk.x = f2bfbits((v[j].x - mean) * rstd * gg.x + bb.x);
    pk.y = f2bfbits((v[j].y - mean) * rstd * gg.y + bb.y);
    pk.z = f2bfbits((v[j].z - mean) * rstd * gg.z + bb.z);
    pk.w = f2bfbits((v[j].w - mean) * rstd * gg.w + bb.w);
    *(ushort4*)&hr[(lane + 64 * j) * 4] = pk;
  }
}

// ---------------- LN2 wave-per-row: row = x+P0+P1; out; h2 = LN(row); top-2 router ----------------
__global__ __launch_bounds__(256) void ln2w_k(
    const float* __restrict__ x, const float* __restrict__ P,
    const float* __restrict__ g, const float* __restrict__ bta,
    float* __restrict__ out, bf16* __restrict__ h, const float* __restrict__ Wr,
    int* __restrict__ top_i, float* __restrict__ top_w)
{
  const int lane = threadIdx.x & 63, w = threadIdx.x >> 6;
  const int row = blockIdx.x * 4 + w;
  const float4* xr = (const float4*)(x + (size_t)row * kEMB);
  const float4* p0 = (const float4*)(P + (size_t)row * kEMB);
  const float4* p1 = (const float4*)(P + (size_t)(kT + row) * kEMB);
  float4* outr = (float4*)(out + (size_t)row * kEMB);
  float4 v[4];
  #pragma unroll
  for (int j = 0; j < 4; j++){
    const float4 a = xr[lane + 64 * j], b = p0[lane + 64 * j], c = p1[lane + 64 * j];
    v[j].x = a.x + b.x + c.x; v[j].y = a.y + b.y + c.y;
    v[j].z = a.z + b.z + c.z; v[j].w = a.w + b.w + c.w;
    outr[lane + 64 * j] = v[j];
  }
  float s = 0.f;
  #pragma unroll
  for (int j = 0; j < 4; j++) s += v[j].x + v[j].y + v[j].z + v[j].w;
  s = wave_sum64(s);
  const float mean = s * (1.0f / kEMB);
  float ss = 0.f;
  #pragma unroll
  for (int j = 0; j < 4; j++){
    const float a = v[j].x - mean, b = v[j].y - mean, c = v[j].z - mean, d = v[j].w - mean;
    ss += a*a + b*b + c*c + d*d;
  }
  ss = wave_sum64(ss);
  const float rstd = rsqrtf(ss * (1.0f / kEMB) + 1e-5f);
  unsigned short* hr = (unsigned short*)h + (size_t)row * kEMB;
  float part[8];
  #pragma unroll
  for (int e = 0; e < 8; e++) part[e] = 0.f;
  #pragma unroll
  for (int j = 0; j < 4; j++){
    const float4 gg = ((const float4*)g)[lane + 64 * j];
    const float4 bb = ((const float4*)bta)[lane + 64 * j];
    float n[4];
    n[0] = (v[j].x - mean) * rstd * gg.x + bb.x;
    n[1] = (v[j].y - mean) * rstd * gg.y + bb.y;
    n[2] = (v[j].z - mean) * rstd * gg.z + bb.z;
    n[3] = (v[j].w - mean) * rstd * gg.w + bb.w;
    ushort4 pk;
    pk.x = f2bfbits(n[0]); pk.y = f2bfbits(n[1]); pk.z = f2bfbits(n[2]); pk.w = f2bfbits(n[3]);
    *(ushort4*)&hr[(lane + 64 * j) * 4] = pk;
    const float* wrp = Wr + (size_t)(lane + 64 * j) * 4 * kNE;
    #pragma unroll
    for (int i = 0; i < 4; i++)
      #pragma unroll
      for (int e = 0; e < 8; e++) part[e] += n[i] * wrp[i * kNE + e];
  }
  #pragma unroll
  for (int xm = 1; xm < 64; xm <<= 1)
    #pragma unroll
    for (int e = 0; e < 8; e++) part[e] += __shfl_xor(part[e], xm, 64);
  if (lane == 0){
    int i0 = 0; float v0 = part[0];
    #pragma unroll
    for (int e = 1; e < 8; e++) if (part[e] > v0){ v0 = part[e]; i0 = e; }
    int i1 = -1; float v1 = -3.4e38f;
    #pragma unroll
    for (int e = 0; e < 8; e++) if (e != i0 && part[e] > v1){ v1 = part[e]; i1 = e; }
    const float w0 = 1.0f / (1.0f + __expf(v1 - v0));
    top_i[row * 2] = i0; top_i[row * 2 + 1] = i1;
    top_w[row * 2] = w0; top_w[row * 2 + 1] = 1.0f - w0;
  }
}

// ---------------- 128x128 bf16 MFMA GEMM, dbuf (R4-proven loop) — dense modes ----------------
// MODE 1: split-K x2 (blockIdx.z = half), fdst[z*kT*kEMB + ...] = partial fp32
// MODE 4: fused QKV: N=3072, sec=gn>>10 -> q(*0.125*log2e)/k/v scattered to [b,h,l,d]
template<int MODE>
__global__ __launch_bounds__(256) void gemm_k(
    const bf16* __restrict__ A, const bf16* __restrict__ BT, int K,
    float* __restrict__ fdst, bf16* __restrict__ bdst)
{
  __shared__ alignas(16) unsigned short As[2][128 * 64];
  __shared__ alignas(16) unsigned short Bs[2][128 * 64];
  const int tid = threadIdx.x, lane = tid & 63, w = tid >> 6;
  const int wr = w >> 1, wc = w & 1;
  const int bx = blockIdx.x, by = blockIdx.y;
  int kt0 = 0, nkt = K / 64;
  if (MODE == 1){ kt0 = blockIdx.z * (K / 2); nkt = K / 128; }
  const int m0 = by * 128, n0 = bx * 128;
  f32x4 acc[4][4] = {};
  const int srow = lane >> 3;          // 0..7
  const int skk  = (lane & 7) * 8;     // k elems (16B chunks)

  auto stage = [&](int t, int buf){
    const int kt = kt0 + t * 64;
    #pragma unroll
    for (int j = 0; j < 4; j++){
      const int rr = w * 32 + j * 8;
      gld_lds16(A + (size_t)(m0 + rr + srow) * K + kt + skk, &As[buf][rr * 64]);
      gld_lds16(BT + (size_t)(n0 + rr + srow) * K + kt + skk, &Bs[buf][rr * 64]);
    }
  };

  stage(0, 0);
  __syncthreads();
  for (int t = 0; t < nkt; t++){
    const int cur = t & 1;
    if (t + 1 < nkt) stage(t + 1, cur ^ 1);
    #pragma unroll
    for (int ks = 0; ks < 2; ks++){
      bf16x8 af[4], bfm[4];
      #pragma unroll
      for (int i = 0; i < 4; i++){
        af[i]  = *(const bf16x8*)&As[cur][(wr * 64 + i * 16 + (lane & 15)) * 64 + ks * 32 + (lane >> 4) * 8];
        bfm[i] = *(const bf16x8*)&Bs[cur][(wc * 64 + i * 16 + (lane & 15)) * 64 + ks * 32 + (lane >> 4) * 8];
      }
      #pragma unroll
      for (int i = 0; i < 4; i++)
        #pragma unroll
        for (int j = 0; j < 4; j++)
          acc[i][j] = __builtin_amdgcn_mfma_f32_16x16x32_bf16(af[i], bfm[j], acc[i][j], 0, 0, 0);
    }
    __syncthreads();
  }

  #pragma unroll
  for (int i = 0; i < 4; i++){
    #pragma unroll
    for (int r = 0; r < 4; r++){
      const int gm = m0 + wr * 64 + i * 16 + (lane >> 4) * 4 + r;
      if (MODE == 1){
        float* pdst = fdst + (size_t)blockIdx.z * kT * kEMB;
        #pragma unroll
        for (int jn = 0; jn < 4; jn++){
          const int gn = n0 + wc * 64 + jn * 16 + (lane & 15);
          pdst[(size_t)gm * kEMB + gn] = acc[i][jn][r];
        }
      } else { // MODE 4
        const int bidx = gm >> 11, l = gm & (kL - 1);
        #pragma unroll
        for (int jn = 0; jn < 4; jn++){
          const int gn = n0 + wc * 64 + jn * 16 + (lane & 15);
          const int sec = gn >> 10;
          const int nn = gn & 1023;
          const int hh = nn >> 6, d = nn & 63;
          // q scale folds 1/sqrt(HD) * log2(e) so attention softmax runs in base 2
          const float val = acc[i][jn][r] * (sec == 0 ? 0.18033688f : 1.0f);
          bdst[(size_t)sec * kT * kEMB + (((size_t)bidx * kNH + hh) * kL + l) * kHD + d] =
              __float2bfloat16(val);
        }
      }
    }
  }
}

// ---------------- grouped MoE GEMM: 128x128, BK=32, A-triple/B-double, one-barrier counted-vmcnt ----------------
// 256 threads (4 waves 2x2). LDS 40KB -> 4 blocks/CU. Per iter issues stageB(t+1) then stageA(t+2);
// at top of iter t outstanding = [B(t) older pair, A(t+1) newer pair] -> vmcnt(2) lands B(t) & all older.
// No vmcnt(0) in-loop. Both-sides 4-chunk XOR swizzle.
// MODE 2: A gathered via rowtok, out = silu(C+bias) [NB=2048, K=1024]
// MODE 3: A contiguous,       out = (C+bias)*roww  [NB=1024, K=2048]
template<int MODE>
__global__ __launch_bounds__(256, 4) void gemm3_k(
    const bf16* __restrict__ A, const bf16* __restrict__ BT, int K,
    bf16* __restrict__ bdst, const float* __restrict__ bias,
    const float* __restrict__ roww, const int* __restrict__ rowtok,
    const int* __restrict__ offs)
{
  __shared__ alignas(16) unsigned short As[3][128 * 32];
  __shared__ alignas(16) unsigned short Bs[2][128 * 32];
  const int tid = threadIdx.x, lane = tid & 63, w = tid >> 6;
  const int wr = w >> 1, wc = w & 1;
  const int e = blockIdx.x & 7, s = blockIdx.x >> 3;
  const int bx = (MODE == 2) ? (s & 15) : (s & 7);
  const int by = (MODE == 2) ? (s >> 4) : (s >> 3);
  const int rbase = offs[e], rend = offs[e + 1];
  if (by * 128 >= rend - rbase) return;
  const int m0 = by * 128, n0 = bx * 128;
  const int NB = (MODE == 2) ? kHID : kEMB;
  const bf16* Bp = BT + (size_t)e * NB * K;
  const float* biasp = bias + e * NB;
  const int nkt = K / 32;
  f32x4 acc[4][4] = {};

  // staging map: chunk sc=tid&3 (16B), row sr0=tid>>2 (pass0) / 64+sr0 (pass1)
  const int sc = tid & 3, sr0 = tid >> 2;
  const int scs = (sc ^ (sr0 & 3)) * 8;       // pre-swizzled source col (elems)
  size_t aoffs[2]; size_t boffs[2];
  {
    int p0 = rbase + m0 + sr0;      if (p0 >= rend) p0 = rbase;
    int p1 = rbase + m0 + 64 + sr0; if (p1 >= rend) p1 = rbase;
    aoffs[0] = (size_t)((MODE == 2) ? rowtok[p0] : p0) * K;
    aoffs[1] = (size_t)((MODE == 2) ? rowtok[p1] : p1) * K;
    boffs[0] = (size_t)(n0 + sr0) * K;
    boffs[1] = (size_t)(n0 + 64 + sr0) * K;
  }

  auto stageA = [&](int t){
    const int b = t % 3; const int kt = t * 32;
    gld_lds16(A + aoffs[0] + kt + scs, &As[b][tid * 8]);
    gld_lds16(A + aoffs[1] + kt + scs, &As[b][(tid + 256) * 8]);
  };
  auto stageB = [&](int t){
    const int b = t & 1; const int kt = t * 32;
    gld_lds16(Bp + boffs[0] + kt + scs, &Bs[b][tid * 8]);
    gld_lds16(Bp + boffs[1] + kt + scs, &Bs[b][(tid + 256) * 8]);
  };

  // prologue: B(0), A(0), A(1)
  stageB(0);
  stageA(0);
  if (nkt > 1) stageA(1);
  asm volatile("s_waitcnt vmcnt(0)" ::: "memory");
  __builtin_amdgcn_s_barrier();

  for (int t = 0; t < nkt; t++){
    if (t > 0){
      if (t + 1 < nkt) { asm volatile("s_waitcnt vmcnt(2)" ::: "memory"); }
      else             { asm volatile("s_waitcnt vmcnt(0)" ::: "memory"); }
      __builtin_amdgcn_s_barrier();
    }
    const int ca = t % 3, cb = t & 1;
    bf16x8 af[4], bfm[4];
    const int cc = lane >> 4;          // 16B chunk 0..3
    #pragma unroll
    for (int i = 0; i < 4; i++){
      const int ar = wr * 64 + i * 16 + (lane & 15);
      af[i] = *(const bf16x8*)&As[ca][ar * 32 + ((cc ^ (ar & 3)) * 8)];
    }
    #pragma unroll
    for (int j = 0; j < 4; j++){
      const int br = wc * 64 + j * 16 + (lane & 15);
      bfm[j] = *(const bf16x8*)&Bs[cb][br * 32 + ((cc ^ (br & 3)) * 8)];
    }
    __builtin_amdgcn_s_setprio(1);
    #pragma unroll
    for (int i = 0; i < 4; i++)
      #pragma unroll
      for (int j = 0; j < 4; j++)
        acc[i][j] = __builtin_amdgcn_mfma_f32_16x16x32_bf16(af[i], bfm[j], acc[i][j], 0, 0, 0);
    __builtin_amdgcn_s_setprio(0);
    if (t + 1 < nkt) stageB(t + 1);
    if (t + 2 < nkt) stageA(t + 2);
  }

  #pragma unroll
  for (int i = 0; i < 4; i++){
    #pragma unroll
    for (int r = 0; r < 4; r++){
      const int p = rbase + m0 + wr * 64 + i * 16 + (lane >> 4) * 4 + r;
      if (p < rend){
        if (MODE == 2){
          #pragma unroll
          for (int jn = 0; jn < 4; jn++){
            const int gn = n0 + wc * 64 + jn * 16 + (lane & 15);
            const float vv = acc[i][jn][r] + biasp[gn];
            bdst[(size_t)p * NB + gn] = __float2bfloat16(vv / (1.0f + __expf(-vv)));
          }
        } else {
          const float wgt = roww[p];
          #pragma unroll
          for (int jn = 0; jn < 4; jn++){
            const int gn = n0 + wc * 64 + jn * 16 + (lane & 15);
            bdst[(size_t)p * NB + gn] = __float2bfloat16((acc[i][jn][r] + biasp[gn]) * wgt);
          }
        }
      }
    }
  }
}

// ---------------- flash attention: 64 q-rows/block, deferred-reduce base-2 softmax ----------------
__global__ __launch_bounds__(256) void attn_k(
    const bf16* __restrict__ q, const bf16* __restrict__ k, const bf16* __restrict__ vt,
    bf16* __restrict__ o, const int* __restrict__ pos)
{
  const int bid = blockIdx.x;
  const int qt = 31 - (bid >> 5);        // descending work order (longest first)
  const int bh = bid & 31;               // bh fastest -> per-XCD K/V L2 affinity
  const int tid = threadIdx.x, lane = tid & 63, w = tid >> 6;
  const unsigned short* qp  = (const unsigned short*)q  + (size_t)bh * kL * kHD;
  const unsigned short* kp  = (const unsigned short*)k  + (size_t)bh * kL * kHD;
  const unsigned short* vtp = (const unsigned short*)vt + (size_t)bh * kHD * kL;
  __shared__ alignas(16) unsigned short Ks[2][64 * 64];   // K[key][d], chunk-swizzled
  __shared__ alignas(16) unsigned short Vt[2][64 * 64];   // V^T[d][key], chunk-swizzled
  __shared__ alignas(16) unsigned short pl[4 * 16 * 72];  // per-wave P [row][key] padded
  const int q0 = qt * 64 + w * 16;
  const int pos0 = pos[0];
  const int wlo = pos0 - kWIN;

  bf16x8 qf[2];
  {
    const int qrow = q0 + (lane & 15);
    #pragma unroll
    for (int ks = 0; ks < 2; ks++)
      qf[ks] = *(const bf16x8*)&qp[(size_t)qrow * kHD + ks * 32 + (lane >> 4) * 8];
  }
  float m_run[4], l_part[4];
  f32x4 oacc[4] = {};
  #pragma unroll
  for (int r = 0; r < 4; r++){ m_run[r] = -1e30f; l_part[r] = 0.f; }

  // stage tile kt into buf: LDS(row, c') = G(row, c'^(row&7)); 16B chunks
  auto stage = [&](int kt, int buf){
    #pragma unroll
    for (int j = 0; j < 2; j++){
      const int r = w * 16 + j * 8 + (lane >> 3);
      const int c = (lane & 7) ^ (r & 7);
      gld_lds16(kp  + (size_t)(kt * 64 + r) * 64 + c * 8, &Ks[buf][(w * 16 + j * 8) * 64]);
      gld_lds16(vtp + (size_t)r * kL + kt * 64 + c * 8,   &Vt[buf][(w * 16 + j * 8) * 64]);
    }
  };

  stage(0, 0);
  for (int kt = 0; kt <= qt; kt++){
    const int buf = kt & 1;
    __syncthreads();               // drains vmcnt -> this tile's stage complete everywhere
    if (kt < qt) stage(kt + 1, buf ^ 1);

    // QK^T (base-2 scaled)
    f32x4 s[4];
    #pragma unroll
    for (int kbk = 0; kbk < 4; kbk++){
      const int row = kbk * 16 + (lane & 15);
      f32x4 a = {0.f, 0.f, 0.f, 0.f};
      #pragma unroll
      for (int ks = 0; ks < 2; ks++){
        const int chnk = ks * 4 + (lane >> 4);
        const bf16x8 kf = *(const bf16x8*)&Ks[buf][row * 64 + ((chnk ^ (row & 7)) * 8)];
        a = __builtin_amdgcn_mfma_f32_16x16x32_bf16(qf[ks], kf, a, 0, 0, 0);
      }
      s[kbk] = a;
    }
    // mask only on diagonal / window-cut tiles (wave-uniform branch)
    const bool needmask = (kt == qt) || (kt * 64 < q0 + 16 + wlo);
    if (needmask){
      #pragma unroll
      for (int kbk = 0; kbk < 4; kbk++){
        const int j = kt * 64 + kbk * 16 + (lane & 15);
        #pragma unroll
        for (int r = 0; r < 4; r++){
          const int i = q0 + (lane >> 4) * 4 + r;
          if (j > i || j < i + wlo) s[kbk][r] = -1e30f;
        }
      }
    }
    // per-lane tile max (no cross-lane reduce on the common path)
    float pmax[4];
    #pragma unroll
    for (int r = 0; r < 4; r++) pmax[r] = s[0][r];
    #pragma unroll
    for (int kbk = 1; kbk < 4; kbk++)
      #pragma unroll
      for (int r = 0; r < 4; r++) pmax[r] = fmaxf(pmax[r], s[kbk][r]);
    bool need = false;
    #pragma unroll
    for (int r = 0; r < 4; r++) need |= (pmax[r] > m_run[r] + 8.0f);
    if (__any(need)){
      float tm[4];
      #pragma unroll
      for (int r = 0; r < 4; r++) tm[r] = pmax[r];
      #pragma unroll
      for (int xm = 1; xm < 16; xm <<= 1)
        #pragma unroll
        for (int r = 0; r < 4; r++) tm[r] = fmaxf(tm[r], __shfl_xor(tm[r], xm, 64));
      #pragma unroll
      for (int r = 0; r < 4; r++){
        const float mn = fmaxf(m_run[r], tm[r]);
        const float corr = exp2f(m_run[r] - mn);
        m_run[r] = mn;
        l_part[r] *= corr;
        #pragma unroll
        for (int db = 0; db < 4; db++) oacc[db][r] *= corr;
      }
    }
    // P = 2^(s - m_run) (bounded by 2^8); per-lane l accumulation only
    #pragma unroll
    for (int kbk = 0; kbk < 4; kbk++)
      #pragma unroll
      for (int r = 0; r < 4; r++){
        const float p = exp2f(s[kbk][r] - m_run[r]);
        s[kbk][r] = p;
        l_part[r] += p;
      }
    // P -> LDS (per-wave region) -> A-fragments
    #pragma unroll
    for (int kbk = 0; kbk < 4; kbk++)
      #pragma unroll
      for (int r = 0; r < 4; r++)
        pl[(w * 16 + (lane >> 4) * 4 + r) * 72 + kbk * 16 + (lane & 15)] = f2bfbits(s[kbk][r]);
    asm volatile("s_waitcnt lgkmcnt(0)" ::: "memory");
    __builtin_amdgcn_sched_barrier(0);
    bf16x8 pa[2];
    #pragma unroll
    for (int ks = 0; ks < 2; ks++)
      pa[ks] = *(const bf16x8*)&pl[(w * 16 + (lane & 15)) * 72 + ks * 32 + (lane >> 4) * 8];
    // PV
    #pragma unroll
    for (int db = 0; db < 4; db++){
      const int row = db * 16 + (lane & 15);
      #pragma unroll
      for (int ks = 0; ks < 2; ks++){
        const int chnk = ks * 4 + (lane >> 4);
        const bf16x8 vf = *(const bf16x8*)&Vt[buf][row * 64 + ((chnk ^ (row & 7)) * 8)];
        oacc[db] = __builtin_amdgcn_mfma_f32_16x16x32_bf16(pa[ks], vf, oacc[db], 0, 0, 0);
      }
    }
  }
  // epilogue: single cross-lane l reduce (16-lane row groups)
  #pragma unroll
  for (int xm = 1; xm < 16; xm <<= 1)
    #pragma unroll
    for (int r = 0; r < 4; r++) l_part[r] += __shfl_xor(l_part[r], xm, 64);
  const int hh = bh & (kNH - 1), bidx = bh >> 4;
  #pragma unroll
  for (int db = 0; db < 4; db++){
    #pragma unroll
    for (int r = 0; r < 4; r++){
      const int i = q0 + (lane >> 4) * 4 + r;
      const int d = db * 16 + (lane & 15);
      o[((size_t)(bidx * kL + i)) * kEMB + hh * kHD + d] = __float2bfloat16(oacc[db][r] / l_part[r]);
    }
  }
}

// ---------------- routing ----------------
// single-block histogram + scan (replaces zero/count/scan)
__global__ void hist_k(const int* __restrict__ top_i, int* __restrict__ offs, int* __restrict__ cursor){
  __shared__ int lc[kNE];
  if (threadIdx.x < kNE) lc[threadIdx.x] = 0;
  __syncthreads();
  for (int i = threadIdx.x; i < kSLOTS; i += 256) atomicAdd(&lc[top_i[i]], 1);
  __syncthreads();
  if (threadIdx.x == 0){
    int o = 0;
    for (int e = 0; e < kNE; e++){ offs[e] = o; cursor[e] = o; o += lc[e]; }
    offs[kNE] = o;
  }
}

__global__ __launch_bounds__(256) void assign_k(const int* __restrict__ top_i, const float* __restrict__ top_w,
                                                int* __restrict__ cursor, int* __restrict__ rowtok,
                                                float* __restrict__ roww, int* __restrict__ tok2row){
  const int idx = blockIdx.x * 256 + threadIdx.x;
  if (idx < kSLOTS){
    const int e = top_i[idx];
    const int p = atomicAdd(&cursor[e], 1);
    rowtok[p] = idx >> 1;
    roww[p] = top_w[idx];
    tok2row[idx] = p;
  }
}

__global__ __launch_bounds__(256) void combine_k(float* __restrict__ out, const bf16* __restrict__ g2,
                                                 const int* __restrict__ tok2row){
  const int t = blockIdx.x, c = threadIdx.x * 4;
  const int r0 = tok2row[t * 2], r1 = tok2row[t * 2 + 1];
  const ushort4 ua = *(const ushort4*)((const unsigned short*)g2 + (size_t)r0 * kEMB + c);
  const ushort4 ub = *(const ushort4*)((const unsigned short*)g2 + (size_t)r1 * kEMB + c);
  float* op = out + (size_t)t * kEMB + c;
  float4 ov = *(float4*)op;
  ov.x += bfbits2f(ua.x) + bfbits2f(ub.x);
  ov.y += bfbits2f(ua.y) + bfbits2f(ub.y);
  ov.z += bfbits2f(ua.z) + bfbits2f(ub.z);
  ov.w += bfbits2f(ua.w) + bfbits2f(ub.w);
  *(float4*)op = ov;
}

// ---------------- launch ----------------
extern "C" void kernel_launch(void* const* d_in, const int* in_sizes, int n_in,
                              void* d_out, int out_size, void* d_ws, size_t ws_size,
                              hipStream_t stream)
{
  const float* x    = (const float*)d_in[0];
  const int*   pos  = (const int*)d_in[1];
  const float* ln1g = (const float*)d_in[2];
  const float* ln1b = (const float*)d_in[3];
  const float* ln2g = (const float*)d_in[4];
  const float* ln2b = (const float*)d_in[5];
  const float* Wq   = (const float*)d_in[6];
  const float* Wk   = (const float*)d_in[7];
  const float* Wv   = (const float*)d_in[8];
  const float* Wo   = (const float*)d_in[9];
  const float* Wr   = (const float*)d_in[10];
  const float* W1   = (const float*)d_in[11];
  const float* b1   = (const float*)d_in[12];
  const float* W2   = (const float*)d_in[13];
  const float* b2   = (const float*)d_in[14];
  float* out = (float*)d_out;

  char* p = (char*)d_ws;
  auto alloc = [&](size_t bytes) -> char* {
    char* r = p; p += (bytes + 255) & ~(size_t)255; return r;
  };
  bf16* WqkvT = (bf16*)alloc((size_t)3 * kEMB * kEMB * 2);  // WqT|WkT|WvT contiguous
  bf16* WoT   = (bf16*)alloc((size_t)kEMB * kEMB * 2);      // contiguous after WqkvT
  bf16* W1T   = (bf16*)alloc((size_t)kNE * kEMB * kHID * 2);
  bf16* W2T   = (bf16*)alloc((size_t)kNE * kEMB * kHID * 2);
  bf16* hbf   = (bf16*)alloc((size_t)kT * kEMB * 2);        // } these three (40MB) are dead
  bf16* qkv   = (bf16*)alloc((size_t)3 * kT * kEMB * 2);    // } after attn -> reused as Pws
  bf16* vtbf  = (bf16*)alloc((size_t)kT * kEMB * 2);
  bf16* abf   = (bf16*)alloc((size_t)kT * kEMB * 2);
  bf16* h2bf  = (bf16*)alloc((size_t)kT * kEMB * 2);
  bf16* hebf  = (bf16*)alloc((size_t)kSLOTS * kHID * 2);
  bf16* g2bf  = (bf16*)alloc((size_t)kSLOTS * kEMB * 2);
  int*   top_i   = (int*)alloc(kSLOTS * 4);
  float* top_w   = (float*)alloc(kSLOTS * 4);
  int*   offs    = (int*)alloc(64);
  int*   cursor  = (int*)alloc(64);
  int*   rowtok  = (int*)alloc(kSLOTS * 4);
  float* rowwgt  = (float*)alloc(kSLOTS * 4);
  int*   tok2row = (int*)alloc(kSLOTS * 4);
  bf16* qbf = qkv;
  bf16* kbf = qkv + (size_t)kT * kEMB;
  bf16* vbf = qkv + (size_t)2 * kT * kEMB;
  float* Pws = (float*)hbf;   // 2 x kT x kEMB fp32 split-K partials (reuses hbf|qkv span)
  (void)in_sizes; (void)n_in; (void)out_size; (void)ws_size;

  // weights -> bf16 transposed (Wq|Wk|Wv|Wo in one dispatch; WoT contiguous after WqkvT)
  tconv4_k<<<dim3(32, 32, 4), 256, 0, stream>>>(Wq, Wk, Wv, Wo, WqkvT);
  tconv_k<<<dim3(64, 32, kNE), 256, 0, stream>>>(W1, W1T, kEMB, kHID);
  tconv_k<<<dim3(32, 64, kNE), 256, 0, stream>>>(W2, W2T, kHID, kEMB);

  // LN1 (wave-per-row)
  lnw_k<<<kT / 4, 256, 0, stream>>>(x, ln1g, ln1b, hbf);

  // fused QKV projection (N=3072; q pre-scaled by 1/sqrt(HD)*log2e)
  gemm_k<4><<<dim3(24, 32), 256, 0, stream>>>(hbf, WqkvT, kEMB, nullptr, qkv);

  // V -> V^T per (b,h)
  vtrans_k<<<dim3(kL / 32, kHD / 32, 32), 256, 0, stream>>>(vbf, vtbf);

  // attention (64 q-rows/block, 1024 blocks)
  attn_k<<<dim3(1024), 256, 0, stream>>>(qbf, kbf, vtbf, abf, pos);

  // Wo split-K x2 -> fp32 partials (residual merge fused into ln2w_k)
  gemm_k<1><<<dim3(8, 32, 2), 256, 0, stream>>>(abf, WoT, kEMB, Pws, nullptr);

  // LN2 + merge + router (wave-per-row, no barriers)
  ln2w_k<<<kT / 4, 256, 0, stream>>>(x, Pws, ln2g, ln2b, out, h2bf, Wr, top_i, top_w);

  // routing (fused histogram+scan, then assign)
  hist_k<<<1, 256, 0, stream>>>(top_i, offs, cursor);
  assign_k<<<kSLOTS / 256, 256, 0, stream>>>(top_i, top_w, cursor, rowtok, rowwgt, tok2row);

  // grouped MoE FFN: A-triple/B-double BK=32 one-barrier kernels, 4 blocks/CU, expert-per-XCD grids
  gemm3_k<2><<<dim3(8 * 32 * 16), 256, 0, stream>>>(h2bf, W1T, kEMB, hebf, b1, nullptr, rowtok, offs);
  gemm3_k<3><<<dim3(8 * 32 * 8), 256, 0, stream>>>(hebf, W2T, kHID, g2bf, b2, rowwgt, nullptr, offs);

  // combine
  combine_k<<<kT, 256, 0, stream>>>(out, g2bf, tok2row);
}